// Round 5
// baseline (734.344 us; speedup 1.0000x reference)
//
#include <hip/hip_runtime.h>
#include <hip/hip_bf16.h>

#define B_ 512
#define T_ 49
#define I_ 96
#define H_ 1024

typedef __attribute__((ext_vector_type(4))) float f32x4;
typedef __attribute__((ext_vector_type(8))) short s16x8;

__device__ __forceinline__ unsigned short f2bf(float f) {
    unsigned int u = __float_as_uint(f);
    unsigned int r = (u + 0x7FFFu + ((u >> 16) & 1u)) >> 16;
    return (unsigned short)r;
}
__device__ __forceinline__ float sigmoidf_(float x) {
    return 1.0f / (1.0f + __expf(-x));
}
__device__ __forceinline__ float tanhf_(float x) {
    return 1.0f - 2.0f / (__expf(2.0f * x) + 1.0f);
}

__device__ __forceinline__ void gload_lds16(const unsigned short* g, unsigned short* l) {
    __builtin_amdgcn_global_load_lds(
        (const __attribute__((address_space(1))) void*)g,
        (__attribute__((address_space(3))) void*)l, 16, 0, 0);
}

// ------------- quantize fp32 -> bf16; x transposed to [t][b][i] -------------
__global__ void quantize_kernel(const float* __restrict__ Whh,
                                const float* __restrict__ Wih,
                                const float* __restrict__ x,
                                unsigned short* __restrict__ Whh_bf,
                                unsigned short* __restrict__ Wih_bf,
                                unsigned short* __restrict__ xT_bf) {
    const long stride = (long)gridDim.x * blockDim.x;
    const long idx = (long)blockIdx.x * blockDim.x + threadIdx.x;

    const long nWhh4 = (long)3 * H_ * H_ / 4;
    const long nWih4 = (long)3 * H_ * I_ / 4;
    const long nX4   = (long)B_ * T_ * I_ / 4;

    for (long i = idx; i < nWhh4; i += stride) {
        float4 v = ((const float4*)Whh)[i];
        ushort4 o; o.x = f2bf(v.x); o.y = f2bf(v.y); o.z = f2bf(v.z); o.w = f2bf(v.w);
        ((ushort4*)Whh_bf)[i] = o;
    }
    for (long i = idx; i < nWih4; i += stride) {
        float4 v = ((const float4*)Wih)[i];
        ushort4 o; o.x = f2bf(v.x); o.y = f2bf(v.y); o.z = f2bf(v.z); o.w = f2bf(v.w);
        ((ushort4*)Wih_bf)[i] = o;
    }
    for (long i = idx; i < nX4; i += stride) {
        float4 v = ((const float4*)x)[i];
        ushort4 o; o.x = f2bf(v.x); o.y = f2bf(v.y); o.z = f2bf(v.z); o.w = f2bf(v.w);
        const long e = i * 4;                 // flat elem idx in [b][t][i]
        const int b  = (int)(e / (T_ * I_));
        const int rm = (int)(e - (long)b * (T_ * I_));
        const int tt = rm / I_;
        const int ii = rm - tt * I_;
        ((ushort4*)xT_bf)[(((long)tt * B_ + b) * I_ + ii) >> 2] = o;
    }
}

// ---------------- one GRU step (v3) ----------------
// 256 blocks x 512 thr (8 waves = 4 mq x 2 kg), 1 block/CU (128 KiB LDS).
// Block tile: 128b x 16j x 3 gates. Wave (mq,kg): rows [mq*32, mq*32+32)
// (Rm=2 reg A-frags), cols all 16j x 3g, K-half kg*512.
// W_hh slice [3][16][1024] resident in LDS per launch, loaded by
// global_load_lds(16B) with XOR-swizzled SOURCE (linear dest, rule #21);
// ds_read side applies byte_off ^= (row&7)<<4 (T2 swizzle).
// k-loop: no barriers. kg partial sums merged via 32KB LDS buffer.
__global__ __launch_bounds__(512)
void gru_step3(const unsigned short* __restrict__ Whh_bf,
               const unsigned short* __restrict__ Wih_bf,
               const unsigned short* __restrict__ xT_bf,
               const float* __restrict__ b_ih,
               const float* __restrict__ b_hh,
               const float* __restrict__ h_in,            // fp32 prev h
               const unsigned short* __restrict__ hbf_in, // bf16 prev h
               float* __restrict__ h_out,
               unsigned short* __restrict__ hbf_out,
               int t, int first)
{
    __shared__ __align__(16) unsigned short Wl[3 * 16 * 1024]; // 96 KiB
    __shared__ __align__(16) f32x4 Red[4 * 8 * 64];            // 32 KiB

    const int tid = threadIdx.x;
    const int w   = tid >> 6;
    const int l   = tid & 63;
    const int l15 = l & 15;
    const int l4  = l >> 4;
    const int mq  = w >> 1;      // 0..3 : 32-row slice
    const int kg  = w & 1;       // 0..1 : K half

    const int bid  = blockIdx.x;
    const int xcd  = bid & 7;
    const int r_   = bid >> 3;
    const int blkb = r_ & 3;              // 4 b-tiles of 128
    const int blkj = xcd * 8 + (r_ >> 2); // 64 j-tiles of 16, XCD-grouped
    const int b0   = blkb * 128;
    const int j0   = blkj * 16;
    const int jg   = j0 + l15;
    const int brow = b0 + mq * 32;

    // ---- W_hh slice -> LDS (async DMA, swizzled source) ----
    if (!first) {
#pragma unroll
        for (int i = 0; i < 12; ++i) {
            const int row  = w * 6 + (i >> 1);    // 0..47 (g*16+jj)
            const int half = i & 1;
            const int g    = row >> 4;
            const int jj   = row & 15;
            const unsigned short* src = Whh_bf
                + ((long)g * H_ + j0 + jj) * H_ + half * 512
                + ((l ^ (jj & 7)) * 8);
            unsigned short* dst = Wl + (g * 16 + jj) * 1024 + half * 512;
            gload_lds16(src, dst);
        }
    }

    f32x4 accR[2], accZ[2], accNh[2], accNi[2];
#pragma unroll
    for (int m = 0; m < 2; ++m) {
        accR[m]  = (f32x4){0.f, 0.f, 0.f, 0.f};
        accZ[m]  = (f32x4){0.f, 0.f, 0.f, 0.f};
        accNh[m] = (f32x4){0.f, 0.f, 0.f, 0.f};
        accNi[m] = (f32x4){0.f, 0.f, 0.f, 0.f};
    }

    // ---- kg0: prefetch blend inputs (fp32 prev h) ----
    float hp[2][4] = {{0.f,0.f,0.f,0.f},{0.f,0.f,0.f,0.f}};
    if (kg == 0 && !first) {
#pragma unroll
        for (int f = 0; f < 2; ++f)
#pragma unroll
            for (int r = 0; r < 4; ++r)
                hp[f][r] = h_in[(long)(brow + f * 16 + l4 * 4 + r) * H_ + jg];
    }

    // ---- kg1: input GEMM gi = x_t @ W_ih^T (K=96, overlaps W DMA) ----
    if (kg == 1) {
        const unsigned short* Ax0 = xT_bf + ((long)t * B_ + brow + l15) * I_ + l4 * 8;
        const unsigned short* Ax1 = Ax0 + 16 * I_;
        const unsigned short* Vr  = Wih_bf + (long)(j0 + l15) * I_ + l4 * 8;
        const unsigned short* Vz  = Wih_bf + (long)(H_ + j0 + l15) * I_ + l4 * 8;
        const unsigned short* Vn  = Wih_bf + (long)(2 * H_ + j0 + l15) * I_ + l4 * 8;
#pragma unroll
        for (int ks = 0; ks < 3; ++ks) {
            s16x8 a0 = *(const s16x8*)(Ax0 + ks * 32);
            s16x8 a1 = *(const s16x8*)(Ax1 + ks * 32);
            s16x8 br = *(const s16x8*)(Vr + ks * 32);
            s16x8 bz = *(const s16x8*)(Vz + ks * 32);
            s16x8 bn = *(const s16x8*)(Vn + ks * 32);
            accR[0]  = __builtin_amdgcn_mfma_f32_16x16x32_bf16(a0, br, accR[0], 0, 0, 0);
            accR[1]  = __builtin_amdgcn_mfma_f32_16x16x32_bf16(a1, br, accR[1], 0, 0, 0);
            accZ[0]  = __builtin_amdgcn_mfma_f32_16x16x32_bf16(a0, bz, accZ[0], 0, 0, 0);
            accZ[1]  = __builtin_amdgcn_mfma_f32_16x16x32_bf16(a1, bz, accZ[1], 0, 0, 0);
            accNi[0] = __builtin_amdgcn_mfma_f32_16x16x32_bf16(a0, bn, accNi[0], 0, 0, 0);
            accNi[1] = __builtin_amdgcn_mfma_f32_16x16x32_bf16(a1, bn, accNi[1], 0, 0, 0);
        }
    }

    // ---- recurrent GEMM: wave's K-half, W from LDS, A ring-3 from global ----
    if (!first) {
        const unsigned short* Ab0 = hbf_in + (long)(brow + l15) * H_ + kg * 512 + l4 * 8;
        const unsigned short* Ab1 = Ab0 + 16 * H_;
        const unsigned short* Wr  = Wl + (0 * 16 + l15) * 1024;
        const unsigned short* Wz  = Wl + (1 * 16 + l15) * 1024;
        const unsigned short* Wn  = Wl + (2 * 16 + l15) * 1024;
        const int swz   = (l15 & 7) << 3;            // XOR in shorts (=<<4 bytes)
        const int kbase = kg * 512 + l4 * 8;

        s16x8 ring[3][4];   // slot = kk%3 (static via full unroll); 2 ks x 2 frags

        // preload kk = 0,1 (overlaps the W DMA / barrier)
#pragma unroll
        for (int p = 0; p < 2; ++p) {
            ring[p][0] = *(const s16x8*)(Ab0 + p * 64);
            ring[p][1] = *(const s16x8*)(Ab0 + p * 64 + 32);
            ring[p][2] = *(const s16x8*)(Ab1 + p * 64);
            ring[p][3] = *(const s16x8*)(Ab1 + p * 64 + 32);
        }

        __syncthreads();   // W slice resident (drains DMA)

#pragma unroll
        for (int kk = 0; kk < 8; ++kk) {
            const int cur = kk % 3;
            const int nxt = (kk + 2) % 3;
            if (kk < 6) {
                ring[nxt][0] = *(const s16x8*)(Ab0 + (kk + 2) * 64);
                ring[nxt][1] = *(const s16x8*)(Ab0 + (kk + 2) * 64 + 32);
                ring[nxt][2] = *(const s16x8*)(Ab1 + (kk + 2) * 64);
                ring[nxt][3] = *(const s16x8*)(Ab1 + (kk + 2) * 64 + 32);
            }
#pragma unroll
            for (int q = 0; q < 2; ++q) {
                const int off = ((kbase + (kk * 2 + q) * 32) ^ swz);
                s16x8 br = *(const s16x8*)(Wr + off);
                s16x8 bz = *(const s16x8*)(Wz + off);
                s16x8 bn = *(const s16x8*)(Wn + off);
                s16x8 a0 = ring[cur][q * 1 + 0];
                s16x8 a1 = ring[cur][q * 1 + 2];
                accR[0]  = __builtin_amdgcn_mfma_f32_16x16x32_bf16(a0, br, accR[0], 0, 0, 0);
                accR[1]  = __builtin_amdgcn_mfma_f32_16x16x32_bf16(a1, br, accR[1], 0, 0, 0);
                accZ[0]  = __builtin_amdgcn_mfma_f32_16x16x32_bf16(a0, bz, accZ[0], 0, 0, 0);
                accZ[1]  = __builtin_amdgcn_mfma_f32_16x16x32_bf16(a1, bz, accZ[1], 0, 0, 0);
                accNh[0] = __builtin_amdgcn_mfma_f32_16x16x32_bf16(a0, bn, accNh[0], 0, 0, 0);
                accNh[1] = __builtin_amdgcn_mfma_f32_16x16x32_bf16(a1, bn, accNh[1], 0, 0, 0);
            }
        }
    }

    // ---- merge kg partials via LDS ----
    __syncthreads();
    if (kg == 1) {
        f32x4* dst = &Red[(mq * 8) * 64 + l];
        dst[0 * 64] = accR[0];  dst[1 * 64] = accR[1];
        dst[2 * 64] = accZ[0];  dst[3 * 64] = accZ[1];
        dst[4 * 64] = accNh[0]; dst[5 * 64] = accNh[1];
        dst[6 * 64] = accNi[0]; dst[7 * 64] = accNi[1];
    }
    __syncthreads();

    if (kg == 0) {
        const f32x4* srcp = &Red[(mq * 8) * 64 + l];
        accR[0]  += srcp[0 * 64]; accR[1]  += srcp[1 * 64];
        accZ[0]  += srcp[2 * 64]; accZ[1]  += srcp[3 * 64];
        accNh[0] += srcp[4 * 64]; accNh[1] += srcp[5 * 64];
        accNi[0] += srcp[6 * 64]; accNi[1] += srcp[7 * 64];

        const float bR   = b_ih[jg] + b_hh[jg];
        const float bZ   = b_ih[H_ + jg] + b_hh[H_ + jg];
        const float bihN = b_ih[2 * H_ + jg];
        const float bhhN = b_hh[2 * H_ + jg];

#pragma unroll
        for (int f = 0; f < 2; ++f) {
#pragma unroll
            for (int r = 0; r < 4; ++r) {
                const int row = brow + f * 16 + l4 * 4 + r;
                const long off = (long)row * H_ + jg;
                const float rg = sigmoidf_(accR[f][r] + bR);
                const float zg = sigmoidf_(accZ[f][r] + bZ);
                const float ng = tanhf_(accNi[f][r] + bihN + rg * (accNh[f][r] + bhhN));
                const float hn = (1.0f - zg) * ng + zg * hp[f][r];
                h_out[off] = hn;
                hbf_out[off] = f2bf(hn);
            }
        }
    }
}

extern "C" void kernel_launch(void* const* d_in, const int* in_sizes, int n_in,
                              void* d_out, int out_size, void* d_ws, size_t ws_size,
                              hipStream_t stream) {
    const float* enc_in = (const float*)d_in[0];
    const float* W_ih   = (const float*)d_in[1];
    const float* W_hh   = (const float*)d_in[2];
    const float* b_ih   = (const float*)d_in[3];
    const float* b_hh   = (const float*)d_in[4];
    float* out = (float*)d_out;

    char* ws = (char*)d_ws;
    unsigned short* Whh_bf = (unsigned short*)(ws);             // 6,291,456 B
    unsigned short* Wih_bf = (unsigned short*)(ws + 6291456);   //   589,824 B
    unsigned short* xT_bf  = (unsigned short*)(ws + 6881280);   // 4,816,896 B
    float* hA              = (float*)(ws + 11698176);           // 2,097,152 B
    float* hB              = (float*)(ws + 13795328);           // 2,097,152 B
    unsigned short* hbfA   = (unsigned short*)(ws + 15892480);  // 1,048,576 B
    unsigned short* hbfB   = (unsigned short*)(ws + 16941056);  // 1,048,576 B

    quantize_kernel<<<dim3(1024), dim3(256), 0, stream>>>(W_hh, W_ih, enc_in,
                                                          Whh_bf, Wih_bf, xT_bf);

    for (int t = 0; t < T_; ++t) {
        const int first = (t == 0) ? 1 : 0;
        float* hi; unsigned short* hbi; float* ho; unsigned short* hbo;
        if (t & 1) { hi = hA; hbi = hbfA; ho = hB; hbo = hbfB; }
        else       { hi = hB; hbi = hbfB; ho = hA; hbo = hbfA; }
        if (t == T_ - 1) ho = out;  // last step writes d_out directly
        gru_step3<<<dim3(256), dim3(512), 0, stream>>>(Whh_bf, Wih_bf, xT_bf,
                                                       b_ih, b_hh, hi, hbi, ho, hbo,
                                                       t, first);
    }
}